// Round 1
// baseline (617.155 us; speedup 1.0000x reference)
//
#include <hip/hip_runtime.h>

#define N_ROWS 8192
#define NX     4096
#define DIM    512
#define TILE   64
#define BK     32

#if __has_builtin(__builtin_amdgcn_exp2f)
  #define EXP2F __builtin_amdgcn_exp2f
#else
  #define EXP2F exp2f
#endif

// ws layout (bytes):
//   0      sqrow[8192]  float   (32768 B)
//   32768  colsum[512]  float   ( 2048 B)
//   34816  cvals[5]     float   (   20 B)   cvals[k] = -log2e/(bw*mult_k)
//   34840  acc          double  (    8 B)

__device__ __forceinline__ const float* zrow(const float* X, const float* Y, int r) {
    return (r < NX) ? (X + (size_t)r * DIM) : (Y + (size_t)(r - NX) * DIM);
}

__global__ void k_init(float* colsum) {
    colsum[threadIdx.x] = 0.f;   // 512 threads
}

// one wave per row: sqrow[r] = sum_d Z[r][d]^2
__global__ void k_rowsq(const float* X, const float* Y, float* sqrow) {
    int wave = threadIdx.x >> 6, lane = threadIdx.x & 63;
    int row = blockIdx.x * 4 + wave;
    const float4* z4 = (const float4*)zrow(X, Y, row);
    float4 a = z4[lane], b = z4[lane + 64];
    float s = a.x*a.x + a.y*a.y + a.z*a.z + a.w*a.w
            + b.x*b.x + b.y*b.y + b.z*b.z + b.w*b.w;
    #pragma unroll
    for (int off = 32; off > 0; off >>= 1) s += __shfl_down(s, off);
    if (lane == 0) sqrow[row] = s;
}

// 64 blocks, each a 128-row slab; thread t owns columns 2t,2t+1
__global__ void k_colsum(const float* X, const float* Y, float* colsum) {
    int c = threadIdx.x * 2;
    int r0 = blockIdx.x * 128;
    float s0 = 0.f, s1 = 0.f;
    for (int r = r0; r < r0 + 128; ++r) {
        const float* zr = zrow(X, Y, r);
        float2 v = *(const float2*)(zr + c);
        s0 += v.x; s1 += v.y;
    }
    atomicAdd(&colsum[c], s0);
    atomicAdd(&colsum[c + 1], s1);
}

// bw = (2n*S1 - 2*||colsum||^2) / (n^2 - n); write exp2 constants; zero acc
__global__ void k_bw(const float* sqrow, const float* colsum, float* cvals, double* acc) {
    __shared__ double red[256];
    int t = threadIdx.x;
    double s1 = 0.0;
    for (int i = t; i < N_ROWS; i += 256) s1 += (double)sqrow[i];
    double cs = 0.0;
    for (int d = t; d < DIM; d += 256) { double v = colsum[d]; cs += v * v; }
    red[t] = s1; __syncthreads();
    for (int off = 128; off > 0; off >>= 1) { if (t < off) red[t] += red[t + off]; __syncthreads(); }
    double S1 = red[0]; __syncthreads();
    red[t] = cs; __syncthreads();
    for (int off = 128; off > 0; off >>= 1) { if (t < off) red[t] += red[t + off]; __syncthreads(); }
    if (t == 0) {
        double CS = red[0];
        double n = (double)N_ROWS;
        double sumD2 = 2.0 * n * S1 - 2.0 * CS;
        double bw = sumD2 / (n * n - n);
        const double LOG2E = 1.4426950408889634;
        double mult = 0.25;
        for (int k = 0; k < 5; ++k) {
            cvals[k] = (float)(-LOG2E / (bw * mult));
            mult *= 2.0;
        }
        *acc = 0.0;
    }
}

// 64x64 tile per block over upper triangle of tile grid; 4x4 outputs/thread
__global__ __launch_bounds__(256) void k_pair(const float* __restrict__ X,
                                              const float* __restrict__ Y,
                                              const float* __restrict__ sqrow,
                                              const float* __restrict__ cvals,
                                              double* acc) {
    int ti = blockIdx.x, tj = blockIdx.y;
    if (tj < ti) return;
    __shared__ float As[BK][TILE + 4], Bs[BK][TILE + 4];  // +4 pad: 16B-aligned, bank spread
    int t  = threadIdx.x;
    int tx = t & 15, ty = t >> 4;

    const float* Abase = (ti < 64) ? X + (size_t)ti * TILE * DIM
                                   : Y + (size_t)(ti - 64) * TILE * DIM;
    const float* Bbase = (tj < 64) ? X + (size_t)tj * TILE * DIM
                                   : Y + (size_t)(tj - 64) * TILE * DIM;

    float accd[4][4];
    #pragma unroll
    for (int a = 0; a < 4; ++a)
        #pragma unroll
        for (int b = 0; b < 4; ++b) accd[a][b] = 0.f;

    int lr  = t >> 3;   // 0..31
    int lc4 = t & 7;    // 0..7

    for (int kt = 0; kt < DIM; kt += BK) {
        #pragma unroll
        for (int h = 0; h < 2; ++h) {
            int r = lr + h * 32;
            float4 va = *(const float4*)(Abase + (size_t)r * DIM + kt + lc4 * 4);
            float4 vb = *(const float4*)(Bbase + (size_t)r * DIM + kt + lc4 * 4);
            As[lc4*4+0][r] = va.x; As[lc4*4+1][r] = va.y; As[lc4*4+2][r] = va.z; As[lc4*4+3][r] = va.w;
            Bs[lc4*4+0][r] = vb.x; Bs[lc4*4+1][r] = vb.y; Bs[lc4*4+2][r] = vb.z; Bs[lc4*4+3][r] = vb.w;
        }
        __syncthreads();
        #pragma unroll
        for (int kk = 0; kk < BK; ++kk) {
            float4 a4 = *(const float4*)&As[kk][ty * 4];
            float4 b4 = *(const float4*)&Bs[kk][tx * 4];
            float av[4] = {a4.x, a4.y, a4.z, a4.w};
            float bv[4] = {b4.x, b4.y, b4.z, b4.w};
            #pragma unroll
            for (int a = 0; a < 4; ++a)
                #pragma unroll
                for (int b = 0; b < 4; ++b)
                    accd[a][b] = fmaf(av[a], bv[b], accd[a][b]);
        }
        __syncthreads();
    }

    // epilogue: D2 -> 5-kernel RBF sum, signed accumulate
    float c0 = cvals[0], c1 = cvals[1], c2 = cvals[2], c3 = cvals[3], c4 = cvals[4];
    int i0 = ti * TILE + ty * 4;
    int j0 = tj * TILE + tx * 4;
    float sqi[4], sqj[4];
    #pragma unroll
    for (int a = 0; a < 4; ++a) { sqi[a] = sqrow[i0 + a]; sqj[a] = sqrow[j0 + a]; }

    float s_local = 0.f;
    #pragma unroll
    for (int a = 0; a < 4; ++a) {
        #pragma unroll
        for (int b = 0; b < 4; ++b) {
            float d2 = fmaf(-2.f, accd[a][b], sqi[a] + sqj[b]);
            d2 = fmaxf(d2, 0.f);
            s_local += EXP2F(d2 * c0);
            s_local += EXP2F(d2 * c1);
            s_local += EXP2F(d2 * c2);
            s_local += EXP2F(d2 * c3);
            s_local += EXP2F(d2 * c4);
        }
    }
    #pragma unroll
    for (int off = 32; off > 0; off >>= 1) s_local += __shfl_down(s_local, off);
    __shared__ float wsum[4];
    int lane = t & 63, wv = t >> 6;
    if (lane == 0) wsum[wv] = s_local;
    __syncthreads();
    if (t == 0) {
        float bs = wsum[0] + wsum[1] + wsum[2] + wsum[3];
        double si = (ti < 64) ? 1.0 : -1.0;
        double sj = (tj < 64) ? 1.0 : -1.0;
        double w = si * sj * ((ti == tj) ? 1.0 : 2.0);
        atomicAdd(acc, w * (double)bs);
    }
}

__global__ void k_final(const double* acc, float* out) {
    out[0] = (float)(*acc / ((double)NX * (double)NX));
}

extern "C" void kernel_launch(void* const* d_in, const int* in_sizes, int n_in,
                              void* d_out, int out_size, void* d_ws, size_t ws_size,
                              hipStream_t stream) {
    const float* X = (const float*)d_in[0];
    const float* Y = (const float*)d_in[1];
    float* out = (float*)d_out;

    float*  sqrow  = (float*)d_ws;
    float*  colsum = sqrow + 8192;
    float*  cvals  = (float*)((char*)d_ws + 34816);
    double* acc    = (double*)((char*)d_ws + 34840);

    k_init  <<<1, 512, 0, stream>>>(colsum);
    k_rowsq <<<2048, 256, 0, stream>>>(X, Y, sqrow);
    k_colsum<<<64, 256, 0, stream>>>(X, Y, colsum);
    k_bw    <<<1, 256, 0, stream>>>(sqrow, colsum, cvals, acc);
    k_pair  <<<dim3(128, 128), 256, 0, stream>>>(X, Y, sqrow, cvals, acc);
    k_final <<<1, 1, 0, stream>>>(acc, out);
}

// Round 2
// 327.104 us; speedup vs baseline: 1.8867x; 1.8867x over previous
//
#include <hip/hip_runtime.h>

#define N_ROWS 8192
#define NX     4096
#define DIM    512
#define BT     128          // block tile (rows & cols)
#define NT     64           // N_ROWS / BT tiles per side

typedef __bf16 bf16_t;
typedef bf16_t bf16x8 __attribute__((ext_vector_type(8)));
typedef bf16_t bf16x4 __attribute__((ext_vector_type(4)));
typedef float  f32x4  __attribute__((ext_vector_type(4)));

#if __has_builtin(__builtin_amdgcn_exp2f)
  #define EXP2F __builtin_amdgcn_exp2f
#else
  #define EXP2F exp2f
#endif

// ws layout (bytes):
//   0       sqrow[8192]  float   (32768 B)   exact fp32 row norms
//   32768   colsum[512]  float   ( 2048 B)
//   34816   cvals[5]     float   (   20 B)   cvals[k] = -log2e/(bw*mult_k)
//   34840   acc          double  (    8 B)
//   36864   Zh[8192*512] bf16    (8388608 B) bf16 copy of concat(X,Y)

__device__ __forceinline__ const float* zrow(const float* X, const float* Y, int r) {
    return (r < NX) ? (X + (size_t)r * DIM) : (Y + (size_t)(r - NX) * DIM);
}

__global__ void k_init(float* colsum) {
    colsum[threadIdx.x] = 0.f;   // 512 threads
}

// fp32 -> bf16 copy of Z = concat(X, Y); 4 elements per thread
__global__ void k_split(const float* __restrict__ X, const float* __restrict__ Y,
                        bf16_t* __restrict__ Zh) {
    int idx = (blockIdx.x * 256 + threadIdx.x) * 4;
    const float* src = (idx < NX * DIM) ? (X + idx) : (Y + (idx - NX * DIM));
    float4 v = *(const float4*)src;
    bf16x4 o = { (bf16_t)v.x, (bf16_t)v.y, (bf16_t)v.z, (bf16_t)v.w };
    *(bf16x4*)(Zh + idx) = o;
}

// one wave per row: sqrow[r] = sum_d Z[r][d]^2   (exact fp32)
__global__ void k_rowsq(const float* X, const float* Y, float* sqrow) {
    int wave = threadIdx.x >> 6, lane = threadIdx.x & 63;
    int row = blockIdx.x * 4 + wave;
    const float4* z4 = (const float4*)zrow(X, Y, row);
    float4 a = z4[lane], b = z4[lane + 64];
    float s = a.x*a.x + a.y*a.y + a.z*a.z + a.w*a.w
            + b.x*b.x + b.y*b.y + b.z*b.z + b.w*b.w;
    #pragma unroll
    for (int off = 32; off > 0; off >>= 1) s += __shfl_down(s, off);
    if (lane == 0) sqrow[row] = s;
}

__global__ void k_colsum(const float* X, const float* Y, float* colsum) {
    int c = threadIdx.x * 2;
    int r0 = blockIdx.x * 128;
    float s0 = 0.f, s1 = 0.f;
    for (int r = r0; r < r0 + 128; ++r) {
        const float* zr = zrow(X, Y, r);
        float2 v = *(const float2*)(zr + c);
        s0 += v.x; s1 += v.y;
    }
    atomicAdd(&colsum[c], s0);
    atomicAdd(&colsum[c + 1], s1);
}

// bw = (2n*S1 - 2*||colsum||^2) / (n^2 - n); write exp2 constants; zero acc
__global__ void k_bw(const float* sqrow, const float* colsum, float* cvals, double* acc) {
    __shared__ double red[256];
    int t = threadIdx.x;
    double s1 = 0.0;
    for (int i = t; i < N_ROWS; i += 256) s1 += (double)sqrow[i];
    double cs = 0.0;
    for (int d = t; d < DIM; d += 256) { double v = colsum[d]; cs += v * v; }
    red[t] = s1; __syncthreads();
    for (int off = 128; off > 0; off >>= 1) { if (t < off) red[t] += red[t + off]; __syncthreads(); }
    double S1 = red[0]; __syncthreads();
    red[t] = cs; __syncthreads();
    for (int off = 128; off > 0; off >>= 1) { if (t < off) red[t] += red[t + off]; __syncthreads(); }
    if (t == 0) {
        double CS = red[0];
        double n = (double)N_ROWS;
        double sumD2 = 2.0 * n * S1 - 2.0 * CS;
        double bw = sumD2 / (n * n - n);
        const double LOG2E = 1.4426950408889634;
        double mult = 0.25;
        for (int k = 0; k < 5; ++k) {
            cvals[k] = (float)(-LOG2E / (bw * mult));
            mult *= 2.0;
        }
        *acc = 0.0;
    }
}

// 128x128 tile per block over upper triangle; 4 waves, each 64x64 via 4x4 MFMA grid.
// LDS is fragment-contiguous: chunk (frag f, lane l) = 16 B at (f*64+l)*16.
// Fragment layout (m89/m91): A[m=lane&15][k=(lane>>4)*8+j]; C/D col=lane&15, row=(lane>>4)*4+reg.
__global__ __launch_bounds__(256) void k_pair(const bf16_t* __restrict__ Zh,
                                              const float* __restrict__ sqrow,
                                              const float* __restrict__ cvals,
                                              double* acc) {
    int ti = blockIdx.x, tj = blockIdx.y;
    if (tj < ti) return;
    __shared__ bf16_t As[4096];   // 8 frags * 64 lanes * 8 bf16 = 8 KB
    __shared__ bf16_t Bs[4096];
    __shared__ float wsum[4];

    int t = threadIdx.x, lane = t & 63, wv = t >> 6;
    int wr = wv >> 1, wc = wv & 1;

    // staging decode: 4 chunks/thread (h=0,1 -> A, h=2,3 -> B)
    int soff[4], ldsoff[4];
    #pragma unroll
    for (int h = 0; h < 4; ++h) {
        int c  = t + 256 * h;
        int cc = c & 511;                 // chunk within tile
        int f = cc >> 6, l = cc & 63;
        int r = 16 * f + (l & 15), q = l >> 4;
        int rowbase = ((h < 2) ? ti : tj) * BT;
        soff[h]   = (rowbase + r) * DIM + q * 8;
        ldsoff[h] = cc * 8;
    }

    f32x4 accf[4][4];
    #pragma unroll
    for (int a = 0; a < 4; ++a)
        #pragma unroll
        for (int b = 0; b < 4; ++b)
            accf[a][b] = (f32x4){0.f, 0.f, 0.f, 0.f};

    uint4 ld[4];
    #pragma unroll
    for (int h = 0; h < 4; ++h) ld[h] = *(const uint4*)(Zh + soff[h]);

    for (int kt = 0; kt < DIM; kt += 32) {
        __syncthreads();   // prior iteration's frag reads complete
        #pragma unroll
        for (int h = 0; h < 4; ++h) {
            bf16_t* dst = ((h < 2) ? As : Bs) + ldsoff[h];
            *(uint4*)dst = ld[h];
        }
        if (kt + 32 < DIM) {
            #pragma unroll
            for (int h = 0; h < 4; ++h)
                ld[h] = *(const uint4*)(Zh + soff[h] + kt + 32);
        }
        __syncthreads();   // staging visible
        bf16x8 a[4], b[4];
        #pragma unroll
        for (int aa = 0; aa < 4; ++aa)
            a[aa] = *(const bf16x8*)(As + ((wr * 4 + aa) * 64 + lane) * 8);
        #pragma unroll
        for (int bb = 0; bb < 4; ++bb)
            b[bb] = *(const bf16x8*)(Bs + ((wc * 4 + bb) * 64 + lane) * 8);
        #pragma unroll
        for (int aa = 0; aa < 4; ++aa)
            #pragma unroll
            for (int bb = 0; bb < 4; ++bb)
                accf[aa][bb] = __builtin_amdgcn_mfma_f32_16x16x32_bf16(
                    a[aa], b[bb], accf[aa][bb], 0, 0, 0);
    }

    // epilogue: D2 -> 5-bandwidth RBF sum
    float c0 = cvals[0], c1 = cvals[1], c2 = cvals[2], c3 = cvals[3], c4 = cvals[4];
    int q = lane >> 4, n16 = lane & 15;
    int i0 = ti * BT + wr * 64;
    int j0 = tj * BT + wc * 64;

    float sqi[4][4], sqj[4];
    #pragma unroll
    for (int aa = 0; aa < 4; ++aa)
        #pragma unroll
        for (int r = 0; r < 4; ++r)
            sqi[aa][r] = sqrow[i0 + 16 * aa + q * 4 + r];
    #pragma unroll
    for (int bb = 0; bb < 4; ++bb)
        sqj[bb] = sqrow[j0 + 16 * bb + n16];

    float s_local = 0.f;
    #pragma unroll
    for (int aa = 0; aa < 4; ++aa) {
        #pragma unroll
        for (int bb = 0; bb < 4; ++bb) {
            #pragma unroll
            for (int r = 0; r < 4; ++r) {
                float d2 = fmaf(-2.f, accf[aa][bb][r], sqi[aa][r] + sqj[bb]);
                d2 = fmaxf(d2, 0.f);
                s_local += EXP2F(d2 * c0);
                s_local += EXP2F(d2 * c1);
                s_local += EXP2F(d2 * c2);
                s_local += EXP2F(d2 * c3);
                s_local += EXP2F(d2 * c4);
            }
        }
    }
    #pragma unroll
    for (int off = 32; off > 0; off >>= 1) s_local += __shfl_down(s_local, off);
    if (lane == 0) wsum[wv] = s_local;
    __syncthreads();
    if (t == 0) {
        float bs = wsum[0] + wsum[1] + wsum[2] + wsum[3];
        double si = (ti < NT / 2) ? 1.0 : -1.0;
        double sj = (tj < NT / 2) ? 1.0 : -1.0;
        double w = si * sj * ((ti == tj) ? 1.0 : 2.0);
        atomicAdd(acc, w * (double)bs);
    }
}

__global__ void k_final(const double* acc, float* out) {
    out[0] = (float)(*acc / ((double)NX * (double)NX));
}

extern "C" void kernel_launch(void* const* d_in, const int* in_sizes, int n_in,
                              void* d_out, int out_size, void* d_ws, size_t ws_size,
                              hipStream_t stream) {
    const float* X = (const float*)d_in[0];
    const float* Y = (const float*)d_in[1];
    float* out = (float*)d_out;

    float*  sqrow  = (float*)d_ws;
    float*  colsum = sqrow + 8192;
    float*  cvals  = (float*)((char*)d_ws + 34816);
    double* acc    = (double*)((char*)d_ws + 34840);
    bf16_t* Zh     = (bf16_t*)((char*)d_ws + 36864);

    k_init  <<<1, 512, 0, stream>>>(colsum);
    k_split <<<4096, 256, 0, stream>>>(X, Y, Zh);
    k_rowsq <<<2048, 256, 0, stream>>>(X, Y, sqrow);
    k_colsum<<<64, 256, 0, stream>>>(X, Y, colsum);
    k_bw    <<<1, 256, 0, stream>>>(sqrow, colsum, cvals, acc);
    k_pair  <<<dim3(NT, NT), 256, 0, stream>>>(Zh, sqrow, cvals, acc);
    k_final <<<1, 1, 0, stream>>>(acc, out);
}

// Round 3
// 152.768 us; speedup vs baseline: 4.0398x; 2.1412x over previous
//
#include <hip/hip_runtime.h>

#define N_ROWS 8192
#define NX     4096
#define DIM    512
#define BT     128          // block tile (rows & cols)
#define NT     64           // N_ROWS / BT tiles per side
#define BK     32           // K elements per stage (64 B per row)

typedef __bf16 bf16_t;
typedef bf16_t bf16x8 __attribute__((ext_vector_type(8)));
typedef bf16_t bf16x4 __attribute__((ext_vector_type(4)));
typedef float  f32x4  __attribute__((ext_vector_type(4)));

#if __has_builtin(__builtin_amdgcn_exp2f)
  #define EXP2F __builtin_amdgcn_exp2f
#else
  #define EXP2F exp2f
#endif

// ws layout (bytes):
//   0       sqrow[8192]  float   (32768 B)   exact fp32 row norms
//   32768   colsum[512]  float   ( 2048 B)
//   34816   cvals[5]     float   (   20 B)   cvals[k] = -log2e/(bw*mult_k)
//   34840   acc          double  (    8 B)
//   36864   Zh[8192*512] bf16    (8388608 B) bf16 copy of concat(X,Y)

__device__ __forceinline__ const float* zrow(const float* X, const float* Y, int r) {
    return (r < NX) ? (X + (size_t)r * DIM) : (Y + (size_t)(r - NX) * DIM);
}

// async 16B global -> LDS (lane-contiguous dest: ldsbase + lane*16)
__device__ __forceinline__ void gload_lds16(const bf16_t* g, bf16_t* l) {
    __builtin_amdgcn_global_load_lds(
        (__attribute__((address_space(1))) void*)(void*)(g),
        (__attribute__((address_space(3))) void*)(void*)(l), 16, 0, 0);
}

// fused: bf16 copy + exact fp32 row norms + colsum zero-init. 4 rows/block.
__global__ void k_prep(const float* __restrict__ X, const float* __restrict__ Y,
                       bf16_t* __restrict__ Zh, float* __restrict__ sqrow,
                       float* __restrict__ colsum) {
    int t = threadIdx.x;
    if (blockIdx.x == 0) { colsum[t] = 0.f; colsum[t + 256] = 0.f; }
    int wv = t >> 6, lane = t & 63;
    int row = blockIdx.x * 4 + wv;
    const float4* z4 = (const float4*)zrow(X, Y, row);
    float4 a = z4[lane], b = z4[lane + 64];
    bf16x4 ha = {(bf16_t)a.x, (bf16_t)a.y, (bf16_t)a.z, (bf16_t)a.w};
    bf16x4 hb = {(bf16_t)b.x, (bf16_t)b.y, (bf16_t)b.z, (bf16_t)b.w};
    *(bf16x4*)(Zh + (size_t)row * DIM + lane * 4) = ha;
    *(bf16x4*)(Zh + (size_t)row * DIM + 256 + lane * 4) = hb;
    float s = a.x*a.x + a.y*a.y + a.z*a.z + a.w*a.w
            + b.x*b.x + b.y*b.y + b.z*b.z + b.w*b.w;
    #pragma unroll
    for (int off = 32; off > 0; off >>= 1) s += __shfl_down(s, off);
    if (lane == 0) sqrow[row] = s;
}

__global__ void k_colsum(const float* X, const float* Y, float* colsum) {
    int c = threadIdx.x * 2;
    int r0 = blockIdx.x * 128;
    float s0 = 0.f, s1 = 0.f;
    for (int r = r0; r < r0 + 128; ++r) {
        const float* zr = zrow(X, Y, r);
        float2 v = *(const float2*)(zr + c);
        s0 += v.x; s1 += v.y;
    }
    atomicAdd(&colsum[c], s0);
    atomicAdd(&colsum[c + 1], s1);
}

// bw = (2n*S1 - 2*||colsum||^2) / (n^2 - n); write exp2 constants; zero acc
__global__ void k_bw(const float* sqrow, const float* colsum, float* cvals, double* acc) {
    __shared__ double red[256];
    int t = threadIdx.x;
    double s1 = 0.0;
    for (int i = t; i < N_ROWS; i += 256) s1 += (double)sqrow[i];
    double cs = 0.0;
    for (int d = t; d < DIM; d += 256) { double v = colsum[d]; cs += v * v; }
    red[t] = s1; __syncthreads();
    for (int off = 128; off > 0; off >>= 1) { if (t < off) red[t] += red[t + off]; __syncthreads(); }
    double S1 = red[0]; __syncthreads();
    red[t] = cs; __syncthreads();
    for (int off = 128; off > 0; off >>= 1) { if (t < off) red[t] += red[t + off]; __syncthreads(); }
    if (t == 0) {
        double CS = red[0];
        double n = (double)N_ROWS;
        double sumD2 = 2.0 * n * S1 - 2.0 * CS;
        double bw = sumD2 / (n * n - n);
        const double LOG2E = 1.4426950408889634;
        double mult = 0.25;
        for (int k = 0; k < 5; ++k) {
            cvals[k] = (float)(-LOG2E / (bw * mult));
            mult *= 2.0;
        }
        *acc = 0.0;
    }
}

// 128x128 tile over upper triangle; row-major LDS (pitch 64 B) staged by
// global_load_lds width=16; XOR swizzle on the GLOBAL side keeps frag
// ds_read_b128 conflict-free. 4 waves, each 64x64 via 4x4 grid of 16x16x32.
// Layouts (m89/m91): A[m=lane&15][k=(lane>>4)*8+j]; C/D col=lane&15,
// row=(lane>>4)*4+reg.
__global__ __launch_bounds__(256) void k_pair(const bf16_t* __restrict__ Zh,
                                              const float* __restrict__ sqrow,
                                              const float* __restrict__ cvals,
                                              double* acc) {
    int ti = blockIdx.x, tj = blockIdx.y;
    if (tj < ti) return;
    __shared__ bf16_t As[4096];   // 128 rows * 4 slots * 8 elems = 8 KB
    __shared__ bf16_t Bs[4096];
    __shared__ float wsum[4];

    int t = threadIdx.x, lane = t & 63, wv = t >> 6;
    int wr = wv >> 1, wc = wv & 1;

    // staging: issue h covers chunks h*256+t; chunk c: row r=c>>2, phys slot
    // sq=c&3 holds logical chunk q = sq ^ ((r>>1)&3)  (64 B-coalesced per row)
    const bf16_t* gA[2]; const bf16_t* gB[2];
    bf16_t* ldsA[2]; bf16_t* ldsB[2];
    #pragma unroll
    for (int h = 0; h < 2; ++h) {
        int c = h * 256 + t;
        int r = c >> 2, sq = c & 3;
        int q = sq ^ ((r >> 1) & 3);
        gA[h] = Zh + (size_t)(ti * BT + r) * DIM + q * 8;
        gB[h] = Zh + (size_t)(tj * BT + r) * DIM + q * 8;
        int base = (h * 256 + wv * 64) * 8;   // wave-uniform; lane*16B implicit
        ldsA[h] = As + base;
        ldsB[h] = Bs + base;
    }

    // fragment LDS element offsets (row r, logical k-chunk q16 -> phys slot)
    int n16 = lane & 15, q16 = lane >> 4;
    int aoff[4], boff[4];
    #pragma unroll
    for (int aa = 0; aa < 4; ++aa) {
        int r = 16 * (wr * 4 + aa) + n16;
        aoff[aa] = (r * 4 + (q16 ^ ((r >> 1) & 3))) * 8;
    }
    #pragma unroll
    for (int bb = 0; bb < 4; ++bb) {
        int r = 16 * (wc * 4 + bb) + n16;
        boff[bb] = (r * 4 + (q16 ^ ((r >> 1) & 3))) * 8;
    }

    f32x4 accf[4][4];
    #pragma unroll
    for (int a = 0; a < 4; ++a)
        #pragma unroll
        for (int b = 0; b < 4; ++b)
            accf[a][b] = (f32x4){0.f, 0.f, 0.f, 0.f};

    for (int kt = 0; kt < DIM; kt += BK) {
        if (kt) __syncthreads();   // prev frag reads done before overwrite
        #pragma unroll
        for (int h = 0; h < 2; ++h) {
            gload_lds16(gA[h] + kt, ldsA[h]);
            gload_lds16(gB[h] + kt, ldsB[h]);
        }
        __syncthreads();           // drains vmcnt -> staged data visible
        bf16x8 a[4], b[4];
        #pragma unroll
        for (int aa = 0; aa < 4; ++aa) a[aa] = *(const bf16x8*)(As + aoff[aa]);
        #pragma unroll
        for (int bb = 0; bb < 4; ++bb) b[bb] = *(const bf16x8*)(Bs + boff[bb]);
        #pragma unroll
        for (int aa = 0; aa < 4; ++aa)
            #pragma unroll
            for (int bb = 0; bb < 4; ++bb)
                accf[aa][bb] = __builtin_amdgcn_mfma_f32_16x16x32_bf16(
                    a[aa], b[bb], accf[aa][bb], 0, 0, 0);
    }

    // epilogue: D2 -> 5-bandwidth RBF via squaring chain:
    // c_k halves per k => e_k = e4^(2^(4-k)); 1 exp + 4 muls per d2
    float c4 = cvals[4];
    int i0 = ti * BT + wr * 64;
    int j0 = tj * BT + wc * 64;

    float sqi[4][4], sqj[4];
    #pragma unroll
    for (int aa = 0; aa < 4; ++aa)
        #pragma unroll
        for (int r = 0; r < 4; ++r)
            sqi[aa][r] = sqrow[i0 + 16 * aa + q16 * 4 + r];
    #pragma unroll
    for (int bb = 0; bb < 4; ++bb)
        sqj[bb] = sqrow[j0 + 16 * bb + n16];

    float s_local = 0.f;
    #pragma unroll
    for (int aa = 0; aa < 4; ++aa) {
        #pragma unroll
        for (int bb = 0; bb < 4; ++bb) {
            #pragma unroll
            for (int r = 0; r < 4; ++r) {
                float d2 = fmaf(-2.f, accf[aa][bb][r], sqi[aa][r] + sqj[bb]);
                d2 = fmaxf(d2, 0.f);
                float e4 = EXP2F(d2 * c4);       // smallest |c|
                float e3 = e4 * e4;
                float e2 = e3 * e3;
                float e1 = e2 * e2;
                float e0 = e1 * e1;
                s_local += e4 + e3 + e2 + e1 + e0;
            }
        }
    }
    #pragma unroll
    for (int off = 32; off > 0; off >>= 1) s_local += __shfl_down(s_local, off);
    if (lane == 0) wsum[wv] = s_local;
    __syncthreads();
    if (t == 0) {
        float bs = wsum[0] + wsum[1] + wsum[2] + wsum[3];
        double si = (ti < NT / 2) ? 1.0 : -1.0;
        double sj = (tj < NT / 2) ? 1.0 : -1.0;
        double w = si * sj * ((ti == tj) ? 1.0 : 2.0);
        atomicAdd(acc, w * (double)bs);
    }
}

__global__ void k_final(const double* acc, float* out) {
    out[0] = (float)(*acc / ((double)NX * (double)NX));
}

extern "C" void kernel_launch(void* const* d_in, const int* in_sizes, int n_in,
                              void* d_out, int out_size, void* d_ws, size_t ws_size,
                              hipStream_t stream) {
    const float* X = (const float*)d_in[0];
    const float* Y = (const float*)d_in[1];
    float* out = (float*)d_out;

    float*  sqrow  = (float*)d_ws;
    float*  colsum = sqrow + 8192;
    float*  cvals  = (float*)((char*)d_ws + 34816);
    double* acc    = (double*)((char*)d_ws + 34840);
    bf16_t* Zh     = (bf16_t*)((char*)d_ws + 36864);

    k_prep  <<<2048, 256, 0, stream>>>(X, Y, Zh, sqrow, colsum);
    k_colsum<<<64, 256, 0, stream>>>(X, Y, colsum);
    k_bw    <<<1, 256, 0, stream>>>(sqrow, colsum, cvals, acc);
    k_pair  <<<dim3(NT, NT), 256, 0, stream>>>(Zh, sqrow, cvals, acc);
    k_final <<<1, 1, 0, stream>>>(acc, out);
}